// Round 10
// baseline (3100.805 us; speedup 1.0000x reference)
//
#include <hip/hip_runtime.h>
#include <cstddef>
#include <cstdint>

#define N_NODES 100000
#define N_EDGES 800000
#define EL_TOT  900000      // edges + self loops
#define HID 128
#define H2  192
#define G4  768             // 4*H2
#define CH3 50000           // stage-3 chunk
#define BK  32
#define LDST 32             // UNPADDED: required by global_load_lds lane mapping
#define SCANB 98            // ceil(N_NODES/1024)
#define GEMM_GRID 1568      // swz_grid(N_NODES, 2) -- compile-time constant
#define AGG_GRID 25000

typedef unsigned short bf16;
typedef __attribute__((ext_vector_type(8))) short bf16x8v;
typedef __attribute__((ext_vector_type(4))) float f32x4v;

#define AS1 __attribute__((address_space(1)))
#define AS3 __attribute__((address_space(3)))

// async global->LDS, 16B per lane; lds base must be wave-uniform (lane i -> +i*16B)
__device__ __forceinline__ void async16(const bf16* g, bf16* l) {
    __builtin_amdgcn_global_load_lds((AS1 void*)g, (AS3 void*)l, 16, 0, 0);
}

// ---------------------------------------------------------------- dtype helpers

__device__ __forceinline__ float b2f(bf16 u) {
    return __uint_as_float(((unsigned)u) << 16);
}
__device__ __forceinline__ bf16 f2b(float f) {   // round-nearest-even
    unsigned u = __float_as_uint(f);
    u += 0x7FFFu + ((u >> 16) & 1u);
    return (bf16)(u >> 16);
}
__device__ __forceinline__ void stE(float* p, size_t i, float v) { p[i] = v; }
__device__ __forceinline__ void stE(bf16* p, size_t i, float v) { p[i] = f2b(v); }
__device__ __forceinline__ float ftanh(float x) {
    float cx = fminf(fmaxf(x, -15.f), 15.f);
    float e = __expf(2.f * cx);
    return (e - 1.f) / (e + 1.f);
}

// x0 recompute: column c of node n for one branch
__device__ __forceinline__ float x0_val(int c, int ia, int is_, int n,
                                        const float* __restrict__ embA,
                                        const float* __restrict__ embS,
                                        const float* __restrict__ xflt) {
    return (c < 123) ? (embA[ia * 123 + c] + embS[is_ * 123 + c])
                     : xflt[n * 5 + (c - 123)];
}

// LSTM gate-column permutation: new col j -> orig gate row
__device__ __forceinline__ int lstm_perm(int j) {
    int w = j & 63, tt = j >> 6;
    return (w >> 4) * 192 + tt * 16 + (w & 15);   // gate*192 + unit
}

// XCD-aware swizzle (explicit block id so fat kernels can remap)
__device__ __forceinline__ bool swz_tile(int id, int R, int ntile, int& bm0, int& nt) {
    const int xcd = id & 7;
    const int s = id >> 3;
    nt = s % ntile;
    const int yp = (s / ntile) * 8 + xcd;
    if (yp * 128 >= R) return false;
    bm0 = yp * 128;
    return true;
}
static inline int swz_grid(int R, int ntile) {
    int panels = (R + 127) / 128;
    return 8 * ntile * ((panels + 7) / 8);
}

// ---------------------------------------------------------------- utilities

__global__ void sentinel_kernel(float* out, int n, float val) {
    int t = blockIdx.x * blockDim.x + threadIdx.x;
    if (t < n) out[t] = val;
}

__global__ void bsum_perm_kernel(const float* __restrict__ bih,
                                 const float* __restrict__ bhh,
                                 float* __restrict__ bsum) {
    int t = blockIdx.x * blockDim.x + threadIdx.x;
    if (t >= 4 * G4) return;
    int d = t / G4, j = t % G4;
    int orig = lstm_perm(j);
    bsum[t] = bih[d * G4 + orig] + bhh[d * G4 + orig];
}

// permute gate rows + convert to bf16: out[d][j][k] = in[d][perm(j)][k]
__global__ void lstm_w_perm_kernel(const float* __restrict__ in,
                                   bf16* __restrict__ out, int K) {
    long long t = (long long)blockIdx.x * blockDim.x + threadIdx.x;
    long long tot = 4LL * G4 * K;
    if (t >= tot) return;
    int k = (int)(t % K);
    int j = (int)((t / K) % G4);
    int d = (int)(t / ((long long)G4 * K));
    int orig = lstm_perm(j);
    out[t] = f2b(in[((size_t)d * G4 + orig) * K + k]);
}

// out[bt][m][k] = in[bt][k][m]  ((K,M) -> (M,K) bf16)
__global__ void trans_kernel(const float* __restrict__ in, bf16* __restrict__ out,
                             int batch, int K, int M) {
    long long t = (long long)blockIdx.x * blockDim.x + threadIdx.x;
    long long tot = (long long)batch * K * M;
    if (t >= tot) return;
    int per = K * M;
    int bt = (int)(t / per);
    int rem = (int)(t % per);
    int m = rem / K, k = rem % K;
    out[t] = f2b(in[(size_t)bt * per + (size_t)k * M + m]);
}

// ---------------------------------------------------------------- CSR build

__global__ void deg_kernel(const int* __restrict__ dst, int* __restrict__ deg) {
    int t = blockIdx.x * blockDim.x + threadIdx.x;
    if (t >= EL_TOT) return;
    int d = (t < N_EDGES) ? dst[t] : (t - N_EDGES);
    atomicAdd(&deg[d], 1);
}

__global__ void scan1_kernel(const int* __restrict__ deg0, const int* __restrict__ deg1,
                             int* __restrict__ tmp0, int* __restrict__ tmp1,
                             int* __restrict__ bsums) {
    __shared__ int sdata[1024];
    const int b = blockIdx.y;
    const int* deg = b ? deg1 : deg0;
    int* tmp = b ? tmp1 : tmp0;
    int i = blockIdx.x * 1024 + threadIdx.x;
    int v = (i < N_NODES) ? deg[i] : 0;
    sdata[threadIdx.x] = v;
    __syncthreads();
    for (int off = 1; off < 1024; off <<= 1) {
        int t = (threadIdx.x >= (unsigned)off) ? sdata[threadIdx.x - off] : 0;
        __syncthreads();
        sdata[threadIdx.x] += t;
        __syncthreads();
    }
    if (i < N_NODES) tmp[i] = sdata[threadIdx.x];
    if (threadIdx.x == 1023) bsums[b * SCANB + blockIdx.x] = sdata[1023];
}

__global__ void scan2_kernel(int* __restrict__ bsums) {
    int b = threadIdx.x;
    if (b < 2) {
        int c = 0;
        for (int k = 0; k < SCANB; ++k) {
            int t = bsums[b * SCANB + k];
            bsums[b * SCANB + k] = c;
            c += t;
        }
    }
}

__global__ void scan3_kernel(const int* __restrict__ bsums,
                             const int* __restrict__ deg0, const int* __restrict__ deg1,
                             const int* __restrict__ tmp0, const int* __restrict__ tmp1,
                             int* __restrict__ offs0, int* __restrict__ offs1,
                             int* __restrict__ pos0, int* __restrict__ pos1) {
    const int b = blockIdx.y;
    const int* deg = b ? deg1 : deg0;
    const int* tmp = b ? tmp1 : tmp0;
    int* offs = b ? offs1 : offs0;
    int* pos = b ? pos1 : pos0;
    int carry = bsums[b * SCANB + blockIdx.x];
    int i = blockIdx.x * 1024 + threadIdx.x;
    if (i < N_NODES) {
        int inc = tmp[i] + carry;
        offs[i + 1] = inc;
        pos[i] = inc - deg[i];
    }
    if (i == 0) offs[0] = 0;
}

__global__ void fill_kernel(const int* __restrict__ srcrow,
                            const int* __restrict__ dstrow,
                            int* __restrict__ pos, int* __restrict__ srcs) {
    int t = blockIdx.x * blockDim.x + threadIdx.x;
    if (t >= EL_TOT) return;
    int s, d;
    if (t < N_EDGES) { s = srcrow[t]; d = dstrow[t]; }
    else             { s = d = t - N_EDGES; }
    int p = atomicAdd(&pos[d], 1);
    srcs[p] = s;
}

// ---------------------------------------------------------------- MFMA GEMM
// FROZEN SHAPE (won 3 head-to-heads): 128x128 tile, 4 waves, 32KB LDS,
// VGPR~92, 2-phase double-buffer. Shared buffers passed in (fat-kernel reuse).
// Fused a_src epilogue (as_ != nullptr, M==256): exclusive-owner plain store.
template<typename TC>
__device__ __forceinline__ void gemm128_dev(
    bf16* __restrict__ AsB, bf16* __restrict__ BsB, int bid,
    const bf16* __restrict__ A1, const bf16* __restrict__ B1, int K1,
    TC* __restrict__ C, const float* __restrict__ bias, int R, int M,
    const float* __restrict__ as_, float* __restrict__ asrc) {
    int bm0, nt;
    if (!swz_tile(bid, R, M >> 7, bm0, nt)) return;
    const int bn0 = nt * 128;
    const int tid = threadIdx.x;
    const int lane = tid & 63;
    const int wave = tid >> 6;
    const int wm = (wave & 1) * 64, wn = (wave >> 1) * 64;
    const int l15 = lane & 15;
    const int q8 = (lane >> 4) * 8;
    const int lr = lane >> 2;
    const int lc = (lane & 3) * 8;

    f32x4v acc[4][4];
#pragma unroll
    for (int i = 0; i < 4; ++i)
#pragma unroll
        for (int j = 0; j < 4; ++j) acc[i][j] = (f32x4v)(0.0f);

    const int ns = K1 / BK;
    auto stage = [&](int buf, int s) {
        const int k0 = s * BK;
        bf16* As = AsB + buf * 128 * LDST;
        bf16* Bs = BsB + buf * 128 * LDST;
#pragma unroll
        for (int rnd = 0; rnd < 2; ++rnd) {
            const int rbase = wave * 16 + rnd * 64;
            const int row = rbase + lr;
            int ga = bm0 + row; ga = (ga < R) ? ga : (R - 1);
            async16(A1 + (size_t)ga * K1 + k0 + lc, &As[rbase * LDST]);
            async16(B1 + (size_t)(bn0 + row) * K1 + k0 + lc, &Bs[rbase * LDST]);
        }
    };

    stage(0, 0);
    __syncthreads();
    for (int s = 0; s < ns; ++s) {
        const int cur = s & 1;
        if (s + 1 < ns) stage(cur ^ 1, s + 1);
        const bf16* As = AsB + cur * 128 * LDST;
        const bf16* Bs = BsB + cur * 128 * LDST;
        bf16x8v af[4], bfv[4];
#pragma unroll
        for (int i = 0; i < 4; ++i) {
            af[i]  = *(const bf16x8v*)&As[(wm + i * 16 + l15) * LDST + q8];
            bfv[i] = *(const bf16x8v*)&Bs[(wn + i * 16 + l15) * LDST + q8];
        }
#pragma unroll
        for (int i = 0; i < 4; ++i)
#pragma unroll
            for (int j = 0; j < 4; ++j)
                acc[i][j] = __builtin_amdgcn_mfma_f32_16x16x32_bf16(
                    af[i], bfv[j], acc[i][j], 0, 0, 0);
        __syncthreads();
    }

    const int head = bn0 >> 7;
#pragma unroll
    for (int i = 0; i < 4; ++i) {
        const int row0 = bm0 + wm + i * 16 + (lane >> 4) * 4;
        if (as_) {   // fused a_src for this col-tile (= head); exclusive owner
            float rs[4] = {0.f, 0.f, 0.f, 0.f};
#pragma unroll
            for (int j = 0; j < 4; ++j) {
                const float w = as_[bn0 + wn + j * 16 + l15];
#pragma unroll
                for (int r = 0; r < 4; ++r) rs[r] += w * acc[i][j][r];
            }
#pragma unroll
            for (int m = 1; m < 16; m <<= 1)
#pragma unroll
                for (int r = 0; r < 4; ++r) rs[r] += __shfl_xor(rs[r], m);
            if (l15 == 0) {
#pragma unroll
                for (int r = 0; r < 4; ++r) {
                    const int gr = row0 + r;
                    if (gr < R) asrc[2 * gr + head] = rs[r];
                }
            }
        }
#pragma unroll
        for (int j = 0; j < 4; ++j) {
            const int col = bn0 + wn + j * 16 + l15;
            const float bv = bias ? bias[col] : 0.f;
#pragma unroll
            for (int r = 0; r < 4; ++r) {
                const int gr = row0 + r;
                if (gr < R) stE(C, (size_t)gr * M + col, acc[i][j][r] + bv);
            }
        }
    }
}

// Layer-0 conv GEMM device fn: A built on the fly (K=128), single-buffered.
__device__ __forceinline__ void gemm_x0_dev(
    bf16* __restrict__ As, bf16* __restrict__ Bs, int bid,
    const int* __restrict__ xidx, const float* __restrict__ xflt,
    const float* __restrict__ embA, const float* __restrict__ embS,
    const bf16* __restrict__ B1, bf16* __restrict__ C, int R, int M,
    const float* __restrict__ as_, float* __restrict__ asrc) {
    int bm0, nt;
    if (!swz_tile(bid, R, M >> 7, bm0, nt)) return;
    const int bn0 = nt * 128;
    const int tid = threadIdx.x;
    const int lane = tid & 63;
    const int wave = tid >> 6;
    const int wm = (wave & 1) * 64, wn = (wave >> 1) * 64;
    const int l15 = lane & 15;
    const int q8 = (lane >> 4) * 8;
    const int srow = tid >> 2;
    const int scol = (tid & 3) * 8;
    const int lr = lane >> 2;
    const int lc = (lane & 3) * 8;

    f32x4v acc[4][4];
#pragma unroll
    for (int i = 0; i < 4; ++i)
#pragma unroll
        for (int j = 0; j < 4; ++j) acc[i][j] = (f32x4v)(0.0f);

    for (int k0 = 0; k0 < 128; k0 += BK) {
#pragma unroll
        for (int rnd = 0; rnd < 2; ++rnd) {
            {   // A: computed on the fly -> ds_write
                int row = srow + rnd * 64;
                int ga = bm0 + row; ga = (ga < R) ? ga : (R - 1);
                int ia = xidx[2 * ga], is_ = xidx[2 * ga + 1];
                bf16 tmp[8];
#pragma unroll
                for (int t = 0; t < 8; ++t)
                    tmp[t] = f2b(x0_val(k0 + scol + t, ia, is_, ga, embA, embS, xflt));
                *(int4*)&As[row * LDST + scol] = *(const int4*)tmp;
            }
            {   // B: async
                const int rbase = wave * 16 + rnd * 64;
                int row = rbase + lr;
                async16(B1 + (size_t)(bn0 + row) * 128 + k0 + lc, &Bs[rbase * LDST]);
            }
        }
        __syncthreads();
        bf16x8v af[4], bfv[4];
#pragma unroll
        for (int i = 0; i < 4; ++i) {
            af[i]  = *(const bf16x8v*)&As[(wm + i * 16 + l15) * LDST + q8];
            bfv[i] = *(const bf16x8v*)&Bs[(wn + i * 16 + l15) * LDST + q8];
        }
#pragma unroll
        for (int i = 0; i < 4; ++i)
#pragma unroll
            for (int j = 0; j < 4; ++j)
                acc[i][j] = __builtin_amdgcn_mfma_f32_16x16x32_bf16(
                    af[i], bfv[j], acc[i][j], 0, 0, 0);
        __syncthreads();
    }
    const int head = bn0 >> 7;
#pragma unroll
    for (int i = 0; i < 4; ++i) {
        const int row0 = bm0 + wm + i * 16 + (lane >> 4) * 4;
        {   // fused a_src (exclusive owner -> plain store)
            float rs[4] = {0.f, 0.f, 0.f, 0.f};
#pragma unroll
            for (int j = 0; j < 4; ++j) {
                const float w = as_[bn0 + wn + j * 16 + l15];
#pragma unroll
                for (int r = 0; r < 4; ++r) rs[r] += w * acc[i][j][r];
            }
#pragma unroll
            for (int m = 1; m < 16; m <<= 1)
#pragma unroll
                for (int r = 0; r < 4; ++r) rs[r] += __shfl_xor(rs[r], m);
            if (l15 == 0) {
#pragma unroll
                for (int r = 0; r < 4; ++r) {
                    const int gr = row0 + r;
                    if (gr < R) asrc[2 * gr + head] = rs[r];
                }
            }
        }
#pragma unroll
        for (int j = 0; j < 4; ++j) {
            const int col = bn0 + wn + j * 16 + l15;
#pragma unroll
            for (int r = 0; r < 4; ++r) {
                const int gr = row0 + r;
                if (gr < R) C[(size_t)gr * M + col] = f2b(acc[i][j][r]);
            }
        }
    }
}

// ---------------------------------------------------------------- GAT agg dev

__device__ __forceinline__ float lrelu02(float x) { return x > 0.f ? x : 0.2f * x; }

// one wave per dst node; 4 edges/iter, 16 lanes/edge. EXACT r7/r9 loop body
// (measured best; r8's branchless/unroll-4 variant regressed — do not reapply).
__device__ __forceinline__ void agg_dev(
    int bid,
    const bf16* __restrict__ xh, const float* __restrict__ asrc,
    const float* __restrict__ ad_, const int* __restrict__ offs,
    const int* __restrict__ srcs,
    const bf16* __restrict__ xprev_l, const bf16* __restrict__ xprev_r,
    const int* __restrict__ xidx, const float* __restrict__ xflt,
    const float* __restrict__ embAl, const float* __restrict__ embSl,
    const float* __restrict__ embAr, const float* __restrict__ embSr,
    const float* __restrict__ bias, bf16* __restrict__ outx) {
    int n = (bid * 256 + (int)threadIdx.x) >> 6;
    int lane = threadIdx.x & 63;
    if (n >= N_NODES) return;
    const int start = offs[n], end = offs[n + 1];
    const int l15 = lane & 15;
    const int g = lane >> 4;            // edge slot within quad

    // a_dst for this node from its own xh row (64 lanes x 4 elems)
    float d0, d1;
    {
        uint2 v = *(const uint2*)(xh + (size_t)n * 256 + lane * 4);
        float p = ad_[lane * 4 + 0] * b2f((bf16)(v.x & 0xffffu))
                + ad_[lane * 4 + 1] * b2f((bf16)(v.x >> 16))
                + ad_[lane * 4 + 2] * b2f((bf16)(v.y & 0xffffu))
                + ad_[lane * 4 + 3] * b2f((bf16)(v.y >> 16));
        for (int o = 1; o < 32; o <<= 1) p += __shfl_xor(p, o);
        d0 = __shfl(p, 0);              // head0 = lanes 0..31
        d1 = __shfl(p, 32);             // head1 = lanes 32..63
    }

    float acc0[8] = {0, 0, 0, 0, 0, 0, 0, 0};
    float acc1[8] = {0, 0, 0, 0, 0, 0, 0, 0};
    float ds0 = 0.f, ds1 = 0.f;
#pragma unroll 2
    for (int j = start; j < end; j += 4) {
        int e = j + g;                  // uniform across the 16-lane group
        if (e < end) {
            int s = srcs[e];
            float2 a2 = *(const float2*)(asrc + 2 * s);   // broadcast in group
            float al0 = __expf(lrelu02(a2.x + d0));
            float al1 = __expf(lrelu02(a2.y + d1));
            if (l15 == 0) { ds0 += al0; ds1 += al1; }
            const bf16* row = xh + (size_t)s * 256 + l15 * 8;
            int4 v0 = *(const int4*)row;           // head0 slice
            int4 v1 = *(const int4*)(row + 128);   // head1 slice
            const int* w0 = (const int*)&v0;
            const int* w1 = (const int*)&v1;
#pragma unroll
            for (int t = 0; t < 4; ++t) {
                acc0[2 * t]     += __uint_as_float(((unsigned)w0[t]) << 16) * al0;
                acc0[2 * t + 1] += __uint_as_float(((unsigned)w0[t]) & 0xffff0000u) * al0;
                acc1[2 * t]     += __uint_as_float(((unsigned)w1[t]) << 16) * al1;
                acc1[2 * t + 1] += __uint_as_float(((unsigned)w1[t]) & 0xffff0000u) * al1;
            }
        }
    }
    // reduce across the 4 edge groups
#pragma unroll
    for (int t = 0; t < 8; ++t) {
        acc0[t] += __shfl_xor(acc0[t], 16); acc0[t] += __shfl_xor(acc0[t], 32);
        acc1[t] += __shfl_xor(acc1[t], 16); acc1[t] += __shfl_xor(acc1[t], 32);
    }
    ds0 += __shfl_xor(ds0, 16); ds0 += __shfl_xor(ds0, 32);
    ds1 += __shfl_xor(ds1, 16); ds1 += __shfl_xor(ds1, 32);
    ds0 = __shfl(ds0, 0); ds1 = __shfl(ds1, 0);
    const float inv0 = 1.f / (ds0 + 1e-16f);
    const float inv1 = 1.f / (ds1 + 1e-16f);
    float accm[8];
#pragma unroll
    for (int t = 0; t < 8; ++t)
        accm[t] = 0.5f * (acc0[t] * inv0 + acc1[t] * inv1);   // head mean

    if (lane < 16) {
        const int c0 = l15 * 8;
        const size_t base = (size_t)n * HID + c0;
        float xm[8];
        if (xidx) {
            int ia = xidx[2 * n], is_ = xidx[2 * n + 1];
#pragma unroll
            for (int t = 0; t < 8; ++t)
                xm[t] = 0.5f * (x0_val(c0 + t, ia, is_, n, embAl, embSl, xflt) +
                                x0_val(c0 + t, ia, is_, n, embAr, embSr, xflt));
        } else {
            int4 vl = *(const int4*)(xprev_l + base);
            int4 vr = *(const int4*)(xprev_r + base);
            const int* wl = (const int*)&vl;
            const int* wr = (const int*)&vr;
#pragma unroll
            for (int t = 0; t < 4; ++t) {
                xm[2 * t] = 0.5f * (__uint_as_float(((unsigned)wl[t]) << 16) +
                                    __uint_as_float(((unsigned)wr[t]) << 16));
                xm[2 * t + 1] = 0.5f * (__uint_as_float(((unsigned)wl[t]) & 0xffff0000u) +
                                        __uint_as_float(((unsigned)wr[t]) & 0xffff0000u));
            }
        }
        bf16 res[8];
#pragma unroll
        for (int t = 0; t < 8; ++t)
            res[t] = f2b(xm[t] + fmaxf(0.f, accm[t] + bias[c0 + t]));
        *(int4*)(outx + base) = *(const int4*)res;
    }
}

// ---------------------------------------------------------------- kernels

__global__ __launch_bounds__(256) void mfma_gemm_x0_kernel(
    const int* xidx, const float* xflt, const float* embA, const float* embS,
    const bf16* B1, bf16* C, int R, int M, const float* as_, float* asrc) {
    __shared__ bf16 As[128 * LDST];
    __shared__ bf16 Bs[128 * LDST];
    gemm_x0_dev(As, Bs, blockIdx.x, xidx, xflt, embA, embS, B1, C, R, M, as_, asrc);
}

__global__ __launch_bounds__(256) void agg_kernel(
    const bf16* xh, const float* asrc, const float* ad_, const int* offs,
    const int* srcs, const bf16* xprev_l, const bf16* xprev_r,
    const int* xidx, const float* xflt,
    const float* embAl, const float* embSl,
    const float* embAr, const float* embSr,
    const float* bias, bf16* outx) {
    agg_dev(blockIdx.x, xh, asrc, ad_, offs, srcs, xprev_l, xprev_r,
            xidx, xflt, embAl, embSl, embAr, embSr, bias, outx);
}

// FAT: blocks [0,GEMM_GRID) run the layer-(i>=1) GEMM of one branch; the rest
// run agg of the OTHER branch (disjoint xh/asrc buffers, verified deps).
__global__ __launch_bounds__(256) void fat1_kernel(
    const bf16* gA1, const bf16* gB1, bf16* gC, const float* gas, float* gasrc,
    const bf16* xh, const float* asrc, const float* ad_, const int* offs,
    const int* srcs, const bf16* xprev_l, const bf16* xprev_r,
    const int* xidx, const float* xflt,
    const float* embAl, const float* embSl,
    const float* embAr, const float* embSr,
    const float* bias, bf16* outx) {
    __shared__ bf16 As[2 * 128 * LDST];
    __shared__ bf16 Bs[2 * 128 * LDST];
    if (blockIdx.x < GEMM_GRID) {
        gemm128_dev<bf16>(As, Bs, blockIdx.x, gA1, gB1, 128, gC, nullptr,
                          N_NODES, 256, gas, gasrc);
    } else {
        agg_dev(blockIdx.x - GEMM_GRID, xh, asrc, ad_, offs, srcs,
                xprev_l, xprev_r, xidx, xflt, embAl, embSl, embAr, embSr,
                bias, outx);
    }
}

// FAT0: layer-0 (x0) GEMM of one branch + agg of the other.
__global__ __launch_bounds__(256) void fat0_kernel(
    const int* gxidx, const float* gxflt, const float* gembA, const float* gembS,
    const bf16* gB1, bf16* gC, const float* gas, float* gasrc,
    const bf16* xh, const float* asrc, const float* ad_, const int* offs,
    const int* srcs,
    const int* xidx, const float* xflt,
    const float* embAl, const float* embSl,
    const float* embAr, const float* embSr,
    const float* bias, bf16* outx) {
    __shared__ bf16 As[128 * LDST];
    __shared__ bf16 Bs[128 * LDST];
    if (blockIdx.x < GEMM_GRID) {
        gemm_x0_dev(As, Bs, blockIdx.x, gxidx, gxflt, gembA, gembS, gB1, gC,
                    N_NODES, 256, gas, gasrc);
    } else {
        agg_dev(blockIdx.x - GEMM_GRID, xh, asrc, ad_, offs, srcs,
                nullptr, nullptr, xidx, xflt, embAl, embSl, embAr, embSr,
                bias, outx);
    }
}

// batched stage-3 GEMM: blockIdx.y selects (A, C); B/bias strided by y.
template<typename TC>
__global__ __launch_bounds__(256) void mfma_gemm_b_kernel(
    const bf16* a0, const bf16* a1, const bf16* a2, const bf16* a3,
    const bf16* __restrict__ Bbase,
    TC* c0, TC* c1, TC* c2, TC* c3,
    const float* __restrict__ bias, int R) {
    __shared__ bf16 As[2 * 128 * LDST];
    __shared__ bf16 Bs[2 * 128 * LDST];
    const int y = blockIdx.y;
    const bf16* A1 = (y == 0) ? a0 : (y == 1) ? a1 : (y == 2) ? a2 : a3;
    TC* C = (y == 0) ? c0 : (y == 1) ? c1 : (y == 2) ? c2 : c3;
    gemm128_dev<TC>(As, Bs, blockIdx.x, A1, Bbase + (size_t)y * 128 * 128, 128,
                    C, bias + (size_t)y * 128, R, 128, nullptr, nullptr);
}

// ---------------------------------------------------------------- fused LSTM GEMM
// Round-4-verified shape (frozen). first!=0 => step 0; last!=0 => skip dead
// h/c stores.
__global__ __launch_bounds__(256) void lstm_gemm_kernel(
    const bf16* __restrict__ A1, const bf16* __restrict__ B1,
    const bf16* __restrict__ A2, const bf16* __restrict__ B2,
    const float* __restrict__ bias, bf16* __restrict__ c_state,
    bf16* __restrict__ h_out, const float* __restrict__ aw,
    float* __restrict__ score, int first, int last, int R) {
    __shared__ bf16 As[2][128 * LDST];
    __shared__ bf16 Bs[2][128 * LDST];
    int bm0, nt;
    if (!swz_tile(blockIdx.x, R, G4 >> 7, bm0, nt)) return;
    const int bn0 = nt * 128;
    const int tid = threadIdx.x;
    const int lane = tid & 63;
    const int wave = tid >> 6;
    const int wm = (wave & 1) * 64, wn = (wave >> 1) * 64;
    const int l15 = lane & 15;
    const int q = lane >> 4;
    const int q8 = q * 8;
    const int lr = lane >> 2;
    const int lc = (lane & 3) * 8;

    f32x4v acc[4][4];
#pragma unroll
    for (int i = 0; i < 4; ++i)
#pragma unroll
        for (int j = 0; j < 4; ++j) acc[i][j] = (f32x4v)(0.0f);

    const int n1 = HID / BK;                 // 4
    const int ns = n1 + (first ? 0 : (H2 / BK));

    auto stage = [&](int buf, int s) {
        const bf16* Ap; const bf16* Bp; int K, k0;
        if (s < n1) { Ap = A1; Bp = B1; K = HID; k0 = s * BK; }
        else        { Ap = A2; Bp = B2; K = H2;  k0 = (s - n1) * BK; }
#pragma unroll
        for (int rnd = 0; rnd < 2; ++rnd) {
            const int rbase = wave * 16 + rnd * 64;
            const int row = rbase + lr;
            int ga = bm0 + row; ga = (ga < R) ? ga : (R - 1);
            async16(Ap + (size_t)ga * K + k0 + lc, &As[buf][rbase * LDST]);
            async16(Bp + (size_t)(bn0 + row) * K + k0 + lc, &Bs[buf][rbase * LDST]);
        }
    };

    stage(0, 0);
    __syncthreads();
    for (int s = 0; s < ns; ++s) {
        const int cur = s & 1;
        if (s + 1 < ns) stage(cur ^ 1, s + 1);
        bf16x8v af[4], bfv[4];
#pragma unroll
        for (int i = 0; i < 4; ++i) {
            af[i]  = *(const bf16x8v*)&As[cur][(wm + i * 16 + l15) * LDST + q8];
            bfv[i] = *(const bf16x8v*)&Bs[cur][(wn + i * 16 + l15) * LDST + q8];
        }
#pragma unroll
        for (int i = 0; i < 4; ++i)
#pragma unroll
            for (int j = 0; j < 4; ++j)
                acc[i][j] = __builtin_amdgcn_mfma_f32_16x16x32_bf16(
                    af[i], bfv[j], acc[i][j], 0, 0, 0);
        __syncthreads();
    }

    // ---- fused LSTM cell epilogue
    const int u = ((bn0 + wn) >> 6) * 16 + l15;      // hidden unit 0..191
    const float awu = aw[u];
    float bv[4];
#pragma unroll
    for (int j = 0; j < 4; ++j) bv[j] = bias[bn0 + wn + j * 16 + l15];
    float psum[4][4];
#pragma unroll
    for (int i = 0; i < 4; ++i) {
        const int row0 = bm0 + wm + i * 16 + q * 4;
#pragma unroll
        for (int r = 0; r < 4; ++r) {
            const int gr = row0 + r;
            const bool ok = gr < R;
            float ig = acc[i][0][r] + bv[0];
            float fg = acc[i][1][r] + bv[1];
            float gg = acc[i][2][r] + bv[2];
            float og = acc[i][3][r] + bv[3];
            float si = 1.f / (1.f + __expf(-ig));
            float sf = 1.f / (1.f + __expf(-fg));
            float so = 1.f / (1.f + __expf(-og));
            float co = (ok && !first) ? b2f(c_state[(size_t)gr * H2 + u]) : 0.f;
            float cn = sf * co + si * ftanh(gg);
            float hn = so * ftanh(cn);
            if (ok && !last) {
                c_state[(size_t)gr * H2 + u] = f2b(cn);
                h_out[(size_t)gr * H2 + u] = f2b(hn);
            }
            psum[i][r] = hn * awu;
        }
    }
#pragma unroll
    for (int m = 1; m < 16; m <<= 1)
#pragma unroll
        for (int i = 0; i < 4; ++i)
#pragma unroll
            for (int r = 0; r < 4; ++r)
                psum[i][r] += __shfl_xor(psum[i][r], m);
    if (l15 == 0) {
#pragma unroll
        for (int i = 0; i < 4; ++i)
#pragma unroll
            for (int r = 0; r < 4; ++r) {
                const int gr = bm0 + wm + i * 16 + q * 4 + r;
                if (gr < R) atomicAdd(&score[gr], psum[i][r]);
            }
    }
}

// ---------------------------------------------------------------- JK / final

__global__ __launch_bounds__(256) void jkfin_kernel(
    const float* __restrict__ sb, const bf16* __restrict__ xs0,
    const bf16* __restrict__ xs1, const bf16* __restrict__ xs2,
    bf16* __restrict__ jk) {
    int w = (blockIdx.x * blockDim.x + threadIdx.x) >> 6;
    int lane = threadIdx.x & 63;
    if (w >= N_NODES) return;
    float s0 = sb[w], s1 = sb[N_NODES + w], s2 = sb[2 * N_NODES + w];
    float m = fmaxf(s0, fmaxf(s1, s2));
    float a0 = __expf(s0 - m), a1 = __expf(s1 - m), a2 = __expf(s2 - m);
    float inv = 1.f / (a0 + a1 + a2);
    a0 *= inv; a1 *= inv; a2 *= inv;
    size_t gn = (size_t)w * HID + lane * 2;
#pragma unroll
    for (int t = 0; t < 2; ++t) {
        float v0 = b2f(xs0[gn + t]);
        float v1 = b2f(xs1[gn + t]);
        float v2 = b2f(xs2[gn + t]);
        jk[gn + t] = f2b(v0 * a0 + v1 * a1 + v2 * a2);
    }
}

__global__ __launch_bounds__(256) void final_kernel(
    const float* __restrict__ o0, const float* __restrict__ o1,
    const float* __restrict__ o2, const float* __restrict__ o3,
    const float* __restrict__ lw, float* __restrict__ out, int nloc, long long c3off) {
    int w = (blockIdx.x * blockDim.x + threadIdx.x) >> 6;
    int lane = threadIdx.x & 63;
    if (w >= nloc) return;
    size_t base = (size_t)w * HID;
    float w0 = lw[lane], w1 = lw[64 + lane];
    const float* op[4] = {o0, o1, o2, o3};
    float v[4][2];
    float s[4];
#pragma unroll
    for (int i = 0; i < 4; ++i) {
        v[i][0] = op[i][base + lane];
        v[i][1] = op[i][base + 64 + lane];
        float t = v[i][0] * w0 + v[i][1] * w1;
        for (int o = 1; o < 64; o <<= 1) t += __shfl_xor(t, o);
        s[i] = t;
    }
    float m = fmaxf(fmaxf(s[0], s[1]), fmaxf(s[2], s[3]));
    float e0 = __expf(s[0] - m), e1 = __expf(s[1] - m);
    float e2 = __expf(s[2] - m), e3 = __expf(s[3] - m);
    float inv = 1.f / (e0 + e1 + e2 + e3);
    float r0 = (v[0][0] * e0 + v[1][0] * e1 + v[2][0] * e2 + v[3][0] * e3) * inv;
    float r1 = (v[0][1] * e0 + v[1][1] * e1 + v[2][1] * e2 + v[3][1] * e3) * inv;
    size_t obase = (size_t)(c3off + w) * HID;
    out[obase + lane] = r0;
    out[obase + 64 + lane] = r1;
}

// ---------------------------------------------------------------- entry

static long long align1k(long long x) { return (x + 1023) & ~1023LL; }

extern "C" void kernel_launch(void* const* d_in, const int* in_sizes, int n_in,
                              void* d_out, int out_size, void* d_ws, size_t ws_size,
                              hipStream_t stream) {
    (void)in_sizes; (void)n_in; (void)out_size;
    const int*   x_idx   = (const int*)  d_in[0];
    const float* x_flt   = (const float*)d_in[1];
    const int*   ei_l    = (const int*)  d_in[2];
    const int*   ei_r    = (const int*)  d_in[3];
    const float* emb_aa  = (const float*)d_in[4];
    const float* emb_ss  = (const float*)d_in[5];
    const float* conv_W  = (const float*)d_in[6];
    const float* att_s   = (const float*)d_in[7];
    const float* att_d   = (const float*)d_in[8];
    const float* conv_b  = (const float*)d_in[9];
    const float* Wih     = (const float*)d_in[10];
    const float* Whh     = (const float*)d_in[11];
    const float* bih     = (const float*)d_in[12];
    const float* bhh     = (const float*)d_in[13];
    const float* jkw     = (const float*)d_in[14];
    const float* dummy_W = (const float*)d_in[16];
    const float* dummy_b = (const float*)d_in[17];
    const float* fin_W   = (const float*)d_in[18];
    const float* fin_b   = (const float*)d_in[19];
    const float* last_W  = (const float*)d_in[20];
    float* out = (float*)d_out;

    const long long S = (long long)N_NODES * HID;
    char* ws = (char*)d_ws;
    long long off = 0;

    // fixed-lifetime allocations
    bf16* hist = (bf16*)(ws + off);  off += align1k(6 * S * 2);          // 153.6 MB
    float* scores = (float*)(ws + off); off += align1k(6LL * N_NODES * 4);
    float* bsum   = (float*)(ws + off); off += align1k(4LL * G4 * 4);
    int* bsums    = (int*)(ws + off);  off += align1k(2LL * SCANB * 4);
    bf16* Wih_b   = (bf16*)(ws + off); off += align1k(4LL * G4 * HID * 2);
    bf16* Whh_b   = (bf16*)(ws + off); off += align1k(4LL * G4 * H2 * 2);
    bf16* dummyWt = (bf16*)(ws + off); off += align1k(2LL * 128 * 128 * 2);
    bf16* finWt   = (bf16*)(ws + off); off += align1k(4LL * 128 * 128 * 2);

    // BIG region overlays (ws ~256 MiB):
    //  stage1: xh[0] = slot0; xh[1] = d_out (free until stage2);
    //          slot1: CSR ints + asrc[2] + convWt
    //  stage2: hA = BIG(38.4), c = BIG+slot0(38.4), hB = d_out scratch
    //  stage2-end/3: jkb = BIG base (51.2)
    char* BIG = ws + off;
    const long long slot0 = align1k(2 * S * 2);                         // 51.2 MB
    const long long slot1 = align1k((long long)N_NODES * H2 * 2);       // 38.4 MB
    const long long need = off + slot0 + slot1;

    if ((long long)ws_size < need) {   // diagnosable: 200000 + ws MiB
        float val = 200000.0f + (float)(ws_size >> 20);
        sentinel_kernel<<<(N_NODES * HID + 255) / 256, 256, 0, stream>>>(
            out, N_NODES * HID, val);
        return;
    }

    // stage1 views
    bf16* xhb[2] = { (bf16*)BIG, (bf16*)d_out };   // per-branch xh
    bf16* jkb = (bf16*)BIG;
    int* ibase = (int*)(BIG + slot0);
    int *deg[2], *offs[2], *pos[2], *srcs[2];
    long long io = 0;
    for (int b = 0; b < 2; ++b) {
        deg[b]  = ibase + io; io += N_NODES;
        offs[b] = ibase + io; io += N_NODES + 1;
        pos[b]  = ibase + io; io += N_NODES;
        srcs[b] = ibase + io; io += EL_TOT;
    }
    long long io4a = ((io * 4 + 15) & ~15LL);
    float* asrcb[2] = { (float*)(BIG + slot0 + io4a),
                        (float*)(BIG + slot0 + io4a) + 2LL * N_NODES };
    bf16* convWt = (bf16*)(BIG + slot0 + io4a + 4LL * N_NODES * 4);
    // stage2 views
    bf16* hA = (bf16*)BIG;               // 38.4 of slot0 (xh dead)
    bf16* hB = (bf16*)d_out;             // out as scratch
    bf16* cC = (bf16*)(BIG + slot0);     // slot1 (CSR dead)

    const float* embA[2] = {emb_aa, emb_aa + 26 * 123};
    const float* embS[2] = {emb_ss, emb_ss + 3 * 123};

    // ---- stage 0: weight conversion (LSTM weights gate-permuted) + CSR
    bsum_perm_kernel<<<12, 256, 0, stream>>>(bih, bhh, bsum);
    trans_kernel<<<(6 * 128 * 256 + 255) / 256, 256, 0, stream>>>(
        conv_W, convWt, 6, 128, 256);
    lstm_w_perm_kernel<<<(4 * G4 * HID + 255) / 256, 256, 0, stream>>>(
        Wih, Wih_b, HID);
    lstm_w_perm_kernel<<<(4 * G4 * H2 + 255) / 256, 256, 0, stream>>>(
        Whh, Whh_b, H2);
    trans_kernel<<<(2 * 128 * 128 + 255) / 256, 256, 0, stream>>>(
        dummy_W, dummyWt, 2, 128, 128);
    trans_kernel<<<(4 * 128 * 128 + 255) / 256, 256, 0, stream>>>(
        fin_W, finWt, 4, 128, 128);
    hipMemsetAsync(deg[0], 0, N_NODES * sizeof(int), stream);
    hipMemsetAsync(deg[1], 0, N_NODES * sizeof(int), stream);
    deg_kernel<<<(EL_TOT + 255) / 256, 256, 0, stream>>>(ei_l + N_EDGES, deg[0]);
    deg_kernel<<<(EL_TOT + 255) / 256, 256, 0, stream>>>(ei_r + N_EDGES, deg[1]);
    scan1_kernel<<<dim3(SCANB, 2), 1024, 0, stream>>>(
        deg[0], deg[1], pos[0], pos[1], bsums);
    scan2_kernel<<<1, 64, 0, stream>>>(bsums);
    scan3_kernel<<<dim3(SCANB, 2), 1024, 0, stream>>>(
        bsums, deg[0], deg[1], pos[0], pos[1], offs[0], offs[1], pos[0], pos[1]);
    fill_kernel<<<(EL_TOT + 255) / 256, 256, 0, stream>>>(
        ei_l, ei_l + N_EDGES, pos[0], srcs[0]);
    fill_kernel<<<(EL_TOT + 255) / 256, 256, 0, stream>>>(
        ei_r, ei_r + N_EDGES, pos[1], srcs[1]);

    // ---- stage 1 pipeline: agg(branch b, layer i) overlapped with the NEXT
    // GEMM (other branch) in one fat launch. Deps run strictly launch-to-launch.
    auto Wc = [&](int b, int i) {
        return convWt + (size_t)(b * 3 + i) * 256 * 128; };
    auto AS = [&](int b, int i) {
        return att_s + (size_t)(b * 3 + i) * 2 * HID; };
    auto AD = [&](int b, int i) {
        return att_d + (size_t)(b * 3 + i) * 2 * HID; };
    auto CB = [&](int b, int i) {
        return conv_b + (size_t)(b * 3 + i) * HID; };
    auto HO = [&](int b, int i) {
        return hist + (size_t)(b * 3 + i) * S; };

    // L0: gemm_x0(b=0)
    mfma_gemm_x0_kernel<<<GEMM_GRID, 256, 0, stream>>>(
        x_idx, x_flt, embA[0], embS[0], Wc(0, 0), xhb[0], N_NODES, 256,
        AS(0, 0), asrcb[0]);
    // L1: gemm_x0(b=1) + agg(b=0,i=0)
    fat0_kernel<<<GEMM_GRID + AGG_GRID, 256, 0, stream>>>(
        x_idx, x_flt, embA[1], embS[1], Wc(1, 0), xhb[1], AS(1, 0), asrcb[1],
        xhb[0], asrcb[0], AD(0, 0), offs[0], srcs[0],
        x_idx, x_flt, embA[0], embS[0], embA[1], embS[1],
        CB(0, 0), HO(0, 0));
    // L2: gemm(b=0,i=1) + agg(b=1,i=0)
    fat1_kernel<<<GEMM_GRID + AGG_GRID, 256, 0, stream>>>(
        HO(0, 0), Wc(0, 1), xhb[0], AS(0, 1), asrcb[0],
        xhb[1], asrcb[1], AD(1, 0), offs[1], srcs[1],
        nullptr, nullptr, x_idx, x_flt,
        embA[0], embS[0], embA[1], embS[1], CB(1, 0), HO(1, 0));
    // L3: gemm(b=1,i=1) + agg(b=0,i=1)
    fat1_kernel<<<GEMM_GRID + AGG_GRID, 256, 0, stream>>>(
        HO(1, 0), Wc(1, 1), xhb[1], AS(1, 1), asrcb[1],
        xhb[0], asrcb[0], AD(0, 1), offs[0], srcs[0],
        HO(0, 0), HO(1, 0), nullptr, x_flt,
        embA[0], embS[0], embA[1], embS[1], CB(0, 1), HO(0, 1));
    // L4: gemm(b=0,i=2) + agg(b=1,i=1)
    fat1_kernel<<<GEMM_GRID + AGG_GRID, 256, 0, stream>>>(
        HO(0, 1), Wc(0, 2), xhb[0], AS(0, 2), asrcb[0],
        xhb[1], asrcb[1], AD(1, 1), offs[1], srcs[1],
        HO(0, 0), HO(1, 0), nullptr, x_flt,
        embA[0], embS[0], embA[1], embS[1], CB(1, 1), HO(1, 1));
    // L5: gemm(b=1,i=2) + agg(b=0,i=2)
    fat1_kernel<<<GEMM_GRID + AGG_GRID, 256, 0, stream>>>(
        HO(1, 1), Wc(1, 2), xhb[1], AS(1, 2), asrcb[1],
        xhb[0], asrcb[0], AD(0, 2), offs[0], srcs[0],
        HO(0, 1), HO(1, 1), nullptr, x_flt,
        embA[0], embS[0], embA[1], embS[1], CB(0, 2), HO(0, 2));
    // L6: agg(b=1,i=2)
    agg_kernel<<<AGG_GRID, 256, 0, stream>>>(
        xhb[1], asrcb[1], AD(1, 2), offs[1], srcs[1],
        HO(0, 1), HO(1, 1), nullptr, x_flt,
        embA[0], embS[0], embA[1], embS[1], CB(1, 2), HO(1, 2));

    // ---- stage 2: bi-LSTM JK, fused cell epilogue, combos sequential;
    // h ping-pongs hA <-> hB (d_out scratch); st=2 skips dead h/c stores.
    hipMemsetAsync(scores, 0, (size_t)6 * N_NODES * 4, stream);
    const int gx = swz_grid(N_NODES, 6);
    for (int b = 0; b < 2; ++b) {
        for (int dir = 0; dir < 2; ++dir) {
            const int combo = b * 2 + dir;
            const bf16* Wi = Wih_b + (size_t)combo * G4 * HID;
            const bf16* Wh = Whh_b + (size_t)combo * G4 * H2;
            const float* bs = bsum + (size_t)combo * G4;
            const float* aw = jkw + (size_t)b * 2 * H2 + (size_t)dir * H2;
            for (int st = 0; st < 3; ++st) {
                int l = dir ? (2 - st) : st;
                const bf16* A = hist + (size_t)(b * 3 + l) * S;
                const bf16* hin = (st == 0) ? nullptr : ((st & 1) ? hA : hB);
                bf16* hout = (st & 1) ? hB : hA;
                lstm_gemm_kernel<<<gx, 256, 0, stream>>>(
                    A, Wi, hin, Wh, bs, cC, hout, aw,
                    scores + (size_t)(b * 3 + l) * N_NODES,
                    st == 0 ? 1 : 0, st == 2 ? 1 : 0, N_NODES);
            }
        }
    }
    for (int b = 0; b < 2; ++b)
        jkfin_kernel<<<25000, 256, 0, stream>>>(
            scores + (size_t)b * 3 * N_NODES,
            hist + (size_t)b * 3 * S, hist + (size_t)(b * 3 + 1) * S,
            hist + (size_t)(b * 3 + 2) * S, jkb + (size_t)b * S);

    // ---- stage 3: sq, outs, final combine (scratch = freed hist region)
    float* f3 = (float*)hist;
    bf16* jkl = jkb; bf16* jkr = jkb + S;
    for (long long c3 = 0; c3 < N_NODES; c3 += CH3) {
        int Rr = (int)((N_NODES - c3) < CH3 ? (N_NODES - c3) : CH3);
        float* o0 = f3;
        float* o1 = f3 + 1LL * CH3 * HID;
        float* o2 = f3 + 2LL * CH3 * HID;
        float* o3 = f3 + 3LL * CH3 * HID;
        bf16* sql = (bf16*)(f3 + 4LL * CH3 * HID);
        bf16* sqr = sql + (long long)CH3 * HID;
        mfma_gemm_b_kernel<bf16><<<dim3(swz_grid(Rr, 1), 2), 256, 0, stream>>>(
            jkl + c3 * HID, jkr + c3 * HID, nullptr, nullptr,
            dummyWt, sql, sqr, nullptr, nullptr, dummy_b, Rr);
        mfma_gemm_b_kernel<float><<<dim3(swz_grid(Rr, 1), 4), 256, 0, stream>>>(
            jkl + c3 * HID, sql, jkr + c3 * HID, sqr,
            finWt, o0, o1, o2, o3, fin_b, Rr);
        final_kernel<<<(Rr + 3) / 4, 256, 0, stream>>>(
            o0, o1, o2, o3, last_W, out, Rr, c3);
    }
}

// Round 11
// 2839.834 us; speedup vs baseline: 1.0919x; 1.0919x over previous
//
#include <hip/hip_runtime.h>
#include <cstddef>
#include <cstdint>

#define N_NODES 100000
#define N_EDGES 800000
#define EL_TOT  900000      // edges + self loops
#define HID 128
#define H2  192
#define G4  768             // 4*H2
#define CH3 50000           // stage-3 chunk
#define BK  32
#define LDST 32             // UNPADDED: required by global_load_lds lane mapping
#define SCANB 98            // ceil(N_NODES/1024)

typedef unsigned short bf16;
typedef __attribute__((ext_vector_type(8))) short bf16x8v;
typedef __attribute__((ext_vector_type(4))) float f32x4v;

#define AS1 __attribute__((address_space(1)))
#define AS3 __attribute__((address_space(3)))

// async global->LDS, 16B per lane; lds base must be wave-uniform (lane i -> +i*16B)
__device__ __forceinline__ void async16(const bf16* g, bf16* l) {
    __builtin_amdgcn_global_load_lds((AS1 void*)g, (AS3 void*)l, 16, 0, 0);
}

// ---------------------------------------------------------------- dtype helpers

__device__ __forceinline__ float b2f(bf16 u) {
    return __uint_as_float(((unsigned)u) << 16);
}
__device__ __forceinline__ bf16 f2b(float f) {   // round-nearest-even
    unsigned u = __float_as_uint(f);
    u += 0x7FFFu + ((u >> 16) & 1u);
    return (bf16)(u >> 16);
}
__device__ __forceinline__ void stE(float* p, size_t i, float v) { p[i] = v; }
__device__ __forceinline__ void stE(bf16* p, size_t i, float v) { p[i] = f2b(v); }
__device__ __forceinline__ float ftanh(float x) {
    float cx = fminf(fmaxf(x, -15.f), 15.f);
    float e = __expf(2.f * cx);
    return (e - 1.f) / (e + 1.f);
}

// x0 recompute: column c of node n for one branch
__device__ __forceinline__ float x0_val(int c, int ia, int is_, int n,
                                        const float* __restrict__ embA,
                                        const float* __restrict__ embS,
                                        const float* __restrict__ xflt) {
    return (c < 123) ? (embA[ia * 123 + c] + embS[is_ * 123 + c])
                     : xflt[n * 5 + (c - 123)];
}

// LSTM gate-column permutation: new col j -> orig gate row
__device__ __forceinline__ int lstm_perm(int j) {
    int w = j & 63, tt = j >> 6;
    return (w >> 4) * 192 + tt * 16 + (w & 15);   // gate*192 + unit
}

// XCD-aware swizzle
__device__ __forceinline__ bool swz_tile(int R, int ntile, int& bm0, int& nt) {
    const int id = blockIdx.x;
    const int xcd = id & 7;
    const int s = id >> 3;
    nt = s % ntile;
    const int yp = (s / ntile) * 8 + xcd;
    if (yp * 128 >= R) return false;
    bm0 = yp * 128;
    return true;
}
static inline int swz_grid(int R, int ntile) {
    int panels = (R + 127) / 128;
    return 8 * ntile * ((panels + 7) / 8);
}

// ---------------------------------------------------------------- utilities

__global__ void sentinel_kernel(float* out, int n, float val) {
    int t = blockIdx.x * blockDim.x + threadIdx.x;
    if (t < n) out[t] = val;
}

__global__ void bsum_perm_kernel(const float* __restrict__ bih,
                                 const float* __restrict__ bhh,
                                 float* __restrict__ bsum) {
    int t = blockIdx.x * blockDim.x + threadIdx.x;
    if (t >= 4 * G4) return;
    int d = t / G4, j = t % G4;
    int orig = lstm_perm(j);
    bsum[t] = bih[d * G4 + orig] + bhh[d * G4 + orig];
}

// permute gate rows + convert to bf16: out[d][j][k] = in[d][perm(j)][k]
__global__ void lstm_w_perm_kernel(const float* __restrict__ in,
                                   bf16* __restrict__ out, int K) {
    long long t = (long long)blockIdx.x * blockDim.x + threadIdx.x;
    long long tot = 4LL * G4 * K;
    if (t >= tot) return;
    int k = (int)(t % K);
    int j = (int)((t / K) % G4);
    int d = (int)(t / ((long long)G4 * K));
    int orig = lstm_perm(j);
    out[t] = f2b(in[((size_t)d * G4 + orig) * K + k]);
}

// out[bt][m][k] = in[bt][k][m]  ((K,M) -> (M,K) bf16)
__global__ void trans_kernel(const float* __restrict__ in, bf16* __restrict__ out,
                             int batch, int K, int M) {
    long long t = (long long)blockIdx.x * blockDim.x + threadIdx.x;
    long long tot = (long long)batch * K * M;
    if (t >= tot) return;
    int per = K * M;
    int bt = (int)(t / per);
    int rem = (int)(t % per);
    int m = rem / K, k = rem % K;
    out[t] = f2b(in[(size_t)bt * per + (size_t)k * M + m]);
}

// ---------------------------------------------------------------- CSR build

__global__ void deg_kernel(const int* __restrict__ dst, int* __restrict__ deg) {
    int t = blockIdx.x * blockDim.x + threadIdx.x;
    if (t >= EL_TOT) return;
    int d = (t < N_EDGES) ? dst[t] : (t - N_EDGES);
    atomicAdd(&deg[d], 1);
}

__global__ void scan1_kernel(const int* __restrict__ deg0, const int* __restrict__ deg1,
                             int* __restrict__ tmp0, int* __restrict__ tmp1,
                             int* __restrict__ bsums) {
    __shared__ int sdata[1024];
    const int b = blockIdx.y;
    const int* deg = b ? deg1 : deg0;
    int* tmp = b ? tmp1 : tmp0;
    int i = blockIdx.x * 1024 + threadIdx.x;
    int v = (i < N_NODES) ? deg[i] : 0;
    sdata[threadIdx.x] = v;
    __syncthreads();
    for (int off = 1; off < 1024; off <<= 1) {
        int t = (threadIdx.x >= (unsigned)off) ? sdata[threadIdx.x - off] : 0;
        __syncthreads();
        sdata[threadIdx.x] += t;
        __syncthreads();
    }
    if (i < N_NODES) tmp[i] = sdata[threadIdx.x];
    if (threadIdx.x == 1023) bsums[b * SCANB + blockIdx.x] = sdata[1023];
}

__global__ void scan2_kernel(int* __restrict__ bsums) {
    int b = threadIdx.x;
    if (b < 2) {
        int c = 0;
        for (int k = 0; k < SCANB; ++k) {
            int t = bsums[b * SCANB + k];
            bsums[b * SCANB + k] = c;
            c += t;
        }
    }
}

__global__ void scan3_kernel(const int* __restrict__ bsums,
                             const int* __restrict__ deg0, const int* __restrict__ deg1,
                             const int* __restrict__ tmp0, const int* __restrict__ tmp1,
                             int* __restrict__ offs0, int* __restrict__ offs1,
                             int* __restrict__ pos0, int* __restrict__ pos1) {
    const int b = blockIdx.y;
    const int* deg = b ? deg1 : deg0;
    const int* tmp = b ? tmp1 : tmp0;
    int* offs = b ? offs1 : offs0;
    int* pos = b ? pos1 : pos0;
    int carry = bsums[b * SCANB + blockIdx.x];
    int i = blockIdx.x * 1024 + threadIdx.x;
    if (i < N_NODES) {
        int inc = tmp[i] + carry;
        offs[i + 1] = inc;
        pos[i] = inc - deg[i];
    }
    if (i == 0) offs[0] = 0;
}

__global__ void fill_kernel(const int* __restrict__ srcrow,
                            const int* __restrict__ dstrow,
                            int* __restrict__ pos, int* __restrict__ srcs) {
    int t = blockIdx.x * blockDim.x + threadIdx.x;
    if (t >= EL_TOT) return;
    int s, d;
    if (t < N_EDGES) { s = srcrow[t]; d = dstrow[t]; }
    else             { s = d = t - N_EDGES; }
    int p = atomicAdd(&pos[d], 1);
    srcs[p] = s;
}

// ---------------------------------------------------------------- MFMA GEMM
// FROZEN SHAPE (won 3 head-to-heads: r3 wide-acc lost, r6 wide-wave lost;
// r10 fat-kernel overlap lost to occupancy poisoning):
// 128x128 block tile, 4 waves, 32KB LDS, VGPR~92, 2-phase double-buffer.
// Fused a_src epilogue (as_ != nullptr, M==256): head = col-tile; each
// (row,head) is written by exactly ONE lane-quad of ONE block -> plain store,
// no memset, no atomic.
template<typename TC>
__device__ __forceinline__ void gemm128_body(
    const bf16* __restrict__ A1, const bf16* __restrict__ B1, int K1,
    TC* __restrict__ C, const float* __restrict__ bias, int R, int M,
    int bm0, int bn0, const float* __restrict__ as_, float* __restrict__ asrc) {
    __shared__ bf16 As[2][128 * LDST];
    __shared__ bf16 Bs[2][128 * LDST];
    const int tid = threadIdx.x;
    const int lane = tid & 63;
    const int wave = tid >> 6;
    const int wm = (wave & 1) * 64, wn = (wave >> 1) * 64;
    const int l15 = lane & 15;
    const int q8 = (lane >> 4) * 8;
    const int lr = lane >> 2;
    const int lc = (lane & 3) * 8;

    f32x4v acc[4][4];
#pragma unroll
    for (int i = 0; i < 4; ++i)
#pragma unroll
        for (int j = 0; j < 4; ++j) acc[i][j] = (f32x4v)(0.0f);

    const int ns = K1 / BK;
    auto stage = [&](int buf, int s) {
        const int k0 = s * BK;
#pragma unroll
        for (int rnd = 0; rnd < 2; ++rnd) {
            const int rbase = wave * 16 + rnd * 64;
            const int row = rbase + lr;
            int ga = bm0 + row; ga = (ga < R) ? ga : (R - 1);
            async16(A1 + (size_t)ga * K1 + k0 + lc, &As[buf][rbase * LDST]);
            async16(B1 + (size_t)(bn0 + row) * K1 + k0 + lc, &Bs[buf][rbase * LDST]);
        }
    };

    stage(0, 0);
    __syncthreads();
    for (int s = 0; s < ns; ++s) {
        const int cur = s & 1;
        if (s + 1 < ns) stage(cur ^ 1, s + 1);
        bf16x8v af[4], bfv[4];
#pragma unroll
        for (int i = 0; i < 4; ++i) {
            af[i]  = *(const bf16x8v*)&As[cur][(wm + i * 16 + l15) * LDST + q8];
            bfv[i] = *(const bf16x8v*)&Bs[cur][(wn + i * 16 + l15) * LDST + q8];
        }
#pragma unroll
        for (int i = 0; i < 4; ++i)
#pragma unroll
            for (int j = 0; j < 4; ++j)
                acc[i][j] = __builtin_amdgcn_mfma_f32_16x16x32_bf16(
                    af[i], bfv[j], acc[i][j], 0, 0, 0);
        __syncthreads();
    }

    const int head = bn0 >> 7;
#pragma unroll
    for (int i = 0; i < 4; ++i) {
        const int row0 = bm0 + wm + i * 16 + (lane >> 4) * 4;
        if (as_) {   // fused a_src for this col-tile (= head); exclusive owner
            float rs[4] = {0.f, 0.f, 0.f, 0.f};
#pragma unroll
            for (int j = 0; j < 4; ++j) {
                const float w = as_[bn0 + wn + j * 16 + l15];
#pragma unroll
                for (int r = 0; r < 4; ++r) rs[r] += w * acc[i][j][r];
            }
#pragma unroll
            for (int m = 1; m < 16; m <<= 1)
#pragma unroll
                for (int r = 0; r < 4; ++r) rs[r] += __shfl_xor(rs[r], m);
            if (l15 == 0) {
#pragma unroll
                for (int r = 0; r < 4; ++r) {
                    const int gr = row0 + r;
                    if (gr < R) asrc[2 * gr + head] = rs[r];
                }
            }
        }
#pragma unroll
        for (int j = 0; j < 4; ++j) {
            const int col = bn0 + wn + j * 16 + l15;
            const float bv = bias ? bias[col] : 0.f;
#pragma unroll
            for (int r = 0; r < 4; ++r) {
                const int gr = row0 + r;
                if (gr < R) stE(C, (size_t)gr * M + col, acc[i][j][r] + bv);
            }
        }
    }
}

// general single-panel GEMM (stage-1: M=256 => ntile=2, fused asrc)
template<typename TC>
__global__ __launch_bounds__(256) void mfma_gemm_kernel(
    const bf16* __restrict__ A1, const bf16* __restrict__ B1, int K1,
    TC* __restrict__ C, const float* __restrict__ bias, int R, int M,
    const float* __restrict__ as_, float* __restrict__ asrc) {
    int bm0, nt;
    if (!swz_tile(R, M >> 7, bm0, nt)) return;
    gemm128_body<TC>(A1, B1, K1, C, bias, R, M, bm0, nt * 128, as_, asrc);
}

// batched stage-3 GEMM: blockIdx.y selects (A, C); B/bias strided by y.
template<typename TC>
__global__ __launch_bounds__(256) void mfma_gemm_b_kernel(
    const bf16* a0, const bf16* a1, const bf16* a2, const bf16* a3,
    const bf16* __restrict__ Bbase,
    TC* c0, TC* c1, TC* c2, TC* c3,
    const float* __restrict__ bias, int R) {
    int bm0, nt;
    if (!swz_tile(R, 1, bm0, nt)) return;
    const int y = blockIdx.y;
    const bf16* A1 = (y == 0) ? a0 : (y == 1) ? a1 : (y == 2) ? a2 : a3;
    TC* C = (y == 0) ? c0 : (y == 1) ? c1 : (y == 2) ? c2 : c3;
    gemm128_body<TC>(A1, Bbase + (size_t)y * 128 * 128, 128, C,
                     bias + (size_t)y * 128, R, 128, bm0, 0, nullptr, nullptr);
}

// ---------------------------------------------------------------- fused LSTM GEMM
// Round-4-verified shape (frozen). Permuted col j: lane's 4 j-frags are
// i,f,g,o of ONE unit. Epilogue: LSTM cell + JK score partial.
// first!=0 => step 0 (h panel skipped, c_prev=0).
// last!=0  => step 2: h_out/c_state never read again -> skip both stores.
__global__ __launch_bounds__(256) void lstm_gemm_kernel(
    const bf16* __restrict__ A1, const bf16* __restrict__ B1,
    const bf16* __restrict__ A2, const bf16* __restrict__ B2,
    const float* __restrict__ bias, bf16* __restrict__ c_state,
    bf16* __restrict__ h_out, const float* __restrict__ aw,
    float* __restrict__ score, int first, int last, int R) {
    __shared__ bf16 As[2][128 * LDST];
    __shared__ bf16 Bs[2][128 * LDST];
    int bm0, nt;
    if (!swz_tile(R, G4 >> 7, bm0, nt)) return;
    const int bn0 = nt * 128;
    const int tid = threadIdx.x;
    const int lane = tid & 63;
    const int wave = tid >> 6;
    const int wm = (wave & 1) * 64, wn = (wave >> 1) * 64;
    const int l15 = lane & 15;
    const int q = lane >> 4;
    const int q8 = q * 8;
    const int lr = lane >> 2;
    const int lc = (lane & 3) * 8;

    f32x4v acc[4][4];
#pragma unroll
    for (int i = 0; i < 4; ++i)
#pragma unroll
        for (int j = 0; j < 4; ++j) acc[i][j] = (f32x4v)(0.0f);

    const int n1 = HID / BK;                 // 4
    const int ns = n1 + (first ? 0 : (H2 / BK));

    auto stage = [&](int buf, int s) {
        const bf16* Ap; const bf16* Bp; int K, k0;
        if (s < n1) { Ap = A1; Bp = B1; K = HID; k0 = s * BK; }
        else        { Ap = A2; Bp = B2; K = H2;  k0 = (s - n1) * BK; }
#pragma unroll
        for (int rnd = 0; rnd < 2; ++rnd) {
            const int rbase = wave * 16 + rnd * 64;
            const int row = rbase + lr;
            int ga = bm0 + row; ga = (ga < R) ? ga : (R - 1);
            async16(Ap + (size_t)ga * K + k0 + lc, &As[buf][rbase * LDST]);
            async16(Bp + (size_t)(bn0 + row) * K + k0 + lc, &Bs[buf][rbase * LDST]);
        }
    };

    stage(0, 0);
    __syncthreads();
    for (int s = 0; s < ns; ++s) {
        const int cur = s & 1;
        if (s + 1 < ns) stage(cur ^ 1, s + 1);
        bf16x8v af[4], bfv[4];
#pragma unroll
        for (int i = 0; i < 4; ++i) {
            af[i]  = *(const bf16x8v*)&As[cur][(wm + i * 16 + l15) * LDST + q8];
            bfv[i] = *(const bf16x8v*)&Bs[cur][(wn + i * 16 + l15) * LDST + q8];
        }
#pragma unroll
        for (int i = 0; i < 4; ++i)
#pragma unroll
            for (int j = 0; j < 4; ++j)
                acc[i][j] = __builtin_amdgcn_mfma_f32_16x16x32_bf16(
                    af[i], bfv[j], acc[i][j], 0, 0, 0);
        __syncthreads();
    }

    // ---- fused LSTM cell epilogue
    const int u = ((bn0 + wn) >> 6) * 16 + l15;      // hidden unit 0..191
    const float awu = aw[u];
    float bv[4];
#pragma unroll
    for (int j = 0; j < 4; ++j) bv[j] = bias[bn0 + wn + j * 16 + l15];
    float psum[4][4];
#pragma unroll
    for (int i = 0; i < 4; ++i) {
        const int row0 = bm0 + wm + i * 16 + q * 4;
#pragma unroll
        for (int r = 0; r < 4; ++r) {
            const int gr = row0 + r;
            const bool ok = gr < R;
            float ig = acc[i][0][r] + bv[0];
            float fg = acc[i][1][r] + bv[1];
            float gg = acc[i][2][r] + bv[2];
            float og = acc[i][3][r] + bv[3];
            float si = 1.f / (1.f + __expf(-ig));
            float sf = 1.f / (1.f + __expf(-fg));
            float so = 1.f / (1.f + __expf(-og));
            float co = (ok && !first) ? b2f(c_state[(size_t)gr * H2 + u]) : 0.f;
            float cn = sf * co + si * ftanh(gg);
            float hn = so * ftanh(cn);
            if (ok && !last) {
                c_state[(size_t)gr * H2 + u] = f2b(cn);
                h_out[(size_t)gr * H2 + u] = f2b(hn);
            }
            psum[i][r] = hn * awu;
        }
    }
#pragma unroll
    for (int m = 1; m < 16; m <<= 1)
#pragma unroll
        for (int i = 0; i < 4; ++i)
#pragma unroll
            for (int r = 0; r < 4; ++r)
                psum[i][r] += __shfl_xor(psum[i][r], m);
    if (l15 == 0) {
#pragma unroll
        for (int i = 0; i < 4; ++i)
#pragma unroll
            for (int r = 0; r < 4; ++r) {
                const int gr = bm0 + wm + i * 16 + q * 4 + r;
                if (gr < R) atomicAdd(&score[gr], psum[i][r]);
            }
    }
}

// Layer-0 conv GEMM: A built on the fly from embeddings (K=128 fixed);
// fused a_src epilogue (plain store, exclusive owner).
__global__ __launch_bounds__(256) void mfma_gemm_x0_kernel(
    const int* __restrict__ xidx, const float* __restrict__ xflt,
    const float* __restrict__ embA, const float* __restrict__ embS,
    const bf16* __restrict__ B1, bf16* __restrict__ C, int R, int M,
    const float* __restrict__ as_, float* __restrict__ asrc) {
    __shared__ bf16 As[128 * LDST];
    __shared__ bf16 Bs[128 * LDST];
    int bm0, nt;
    if (!swz_tile(R, M >> 7, bm0, nt)) return;
    const int bn0 = nt * 128;
    const int tid = threadIdx.x;
    const int lane = tid & 63;
    const int wave = tid >> 6;
    const int wm = (wave & 1) * 64, wn = (wave >> 1) * 64;
    const int l15 = lane & 15;
    const int q8 = (lane >> 4) * 8;
    const int srow = tid >> 2;
    const int scol = (tid & 3) * 8;
    const int lr = lane >> 2;
    const int lc = (lane & 3) * 8;

    f32x4v acc[4][4];
#pragma unroll
    for (int i = 0; i < 4; ++i)
#pragma unroll
        for (int j = 0; j < 4; ++j) acc[i][j] = (f32x4v)(0.0f);

    for (int k0 = 0; k0 < 128; k0 += BK) {
#pragma unroll
        for (int rnd = 0; rnd < 2; ++rnd) {
            {   // A: computed on the fly -> ds_write
                int row = srow + rnd * 64;
                int ga = bm0 + row; ga = (ga < R) ? ga : (R - 1);
                int ia = xidx[2 * ga], is_ = xidx[2 * ga + 1];
                bf16 tmp[8];
#pragma unroll
                for (int t = 0; t < 8; ++t)
                    tmp[t] = f2b(x0_val(k0 + scol + t, ia, is_, ga, embA, embS, xflt));
                *(int4*)&As[row * LDST + scol] = *(const int4*)tmp;
            }
            {   // B: async
                const int rbase = wave * 16 + rnd * 64;
                int row = rbase + lr;
                async16(B1 + (size_t)(bn0 + row) * 128 + k0 + lc, &Bs[rbase * LDST]);
            }
        }
        __syncthreads();
        bf16x8v af[4], bfv[4];
#pragma unroll
        for (int i = 0; i < 4; ++i) {
            af[i]  = *(const bf16x8v*)&As[(wm + i * 16 + l15) * LDST + q8];
            bfv[i] = *(const bf16x8v*)&Bs[(wn + i * 16 + l15) * LDST + q8];
        }
#pragma unroll
        for (int i = 0; i < 4; ++i)
#pragma unroll
            for (int j = 0; j < 4; ++j)
                acc[i][j] = __builtin_amdgcn_mfma_f32_16x16x32_bf16(
                    af[i], bfv[j], acc[i][j], 0, 0, 0);
        __syncthreads();
    }
    const int head = bn0 >> 7;
#pragma unroll
    for (int i = 0; i < 4; ++i) {
        const int row0 = bm0 + wm + i * 16 + (lane >> 4) * 4;
        {   // fused a_src (exclusive owner -> plain store)
            float rs[4] = {0.f, 0.f, 0.f, 0.f};
#pragma unroll
            for (int j = 0; j < 4; ++j) {
                const float w = as_[bn0 + wn + j * 16 + l15];
#pragma unroll
                for (int r = 0; r < 4; ++r) rs[r] += w * acc[i][j][r];
            }
#pragma unroll
            for (int m = 1; m < 16; m <<= 1)
#pragma unroll
                for (int r = 0; r < 4; ++r) rs[r] += __shfl_xor(rs[r], m);
            if (l15 == 0) {
#pragma unroll
                for (int r = 0; r < 4; ++r) {
                    const int gr = row0 + r;
                    if (gr < R) asrc[2 * gr + head] = rs[r];
                }
            }
        }
#pragma unroll
        for (int j = 0; j < 4; ++j) {
            const int col = bn0 + wn + j * 16 + l15;
#pragma unroll
            for (int r = 0; r < 4; ++r) {
                const int gr = row0 + r;
                if (gr < R) C[(size_t)gr * M + col] = f2b(acc[i][j][r]);
            }
        }
    }
}

// ---------------------------------------------------------------- GAT agg

__device__ __forceinline__ float lrelu02(float x) { return x > 0.f ? x : 0.2f * x; }

// one wave per dst node; 4 edges/iter, 16 lanes/edge (2x int4/lane = 512B row).
// EXACT round-7 loop body (measured best: 163.4us, VGPR 36, occ 73%);
// r8's branchless-ds + unroll-4 variant regressed to 171us — do not reapply.
__global__ __launch_bounds__(256) void agg_kernel(
    const bf16* __restrict__ xh, const float* __restrict__ asrc,
    const float* __restrict__ ad_, const int* __restrict__ offs,
    const int* __restrict__ srcs,
    const bf16* __restrict__ xprev_l, const bf16* __restrict__ xprev_r,
    const int* __restrict__ xidx, const float* __restrict__ xflt,
    const float* __restrict__ embAl, const float* __restrict__ embSl,
    const float* __restrict__ embAr, const float* __restrict__ embSr,
    const float* __restrict__ bias, bf16* __restrict__ outx) {
    int n = (blockIdx.x * blockDim.x + threadIdx.x) >> 6;
    int lane = threadIdx.x & 63;
    if (n >= N_NODES) return;
    const int start = offs[n], end = offs[n + 1];
    const int l15 = lane & 15;
    const int g = lane >> 4;            // edge slot within quad

    // a_dst for this node from its own xh row (64 lanes x 4 elems)
    float d0, d1;
    {
        uint2 v = *(const uint2*)(xh + (size_t)n * 256 + lane * 4);
        float p = ad_[lane * 4 + 0] * b2f((bf16)(v.x & 0xffffu))
                + ad_[lane * 4 + 1] * b2f((bf16)(v.x >> 16))
                + ad_[lane * 4 + 2] * b2f((bf16)(v.y & 0xffffu))
                + ad_[lane * 4 + 3] * b2f((bf16)(v.y >> 16));
        for (int o = 1; o < 32; o <<= 1) p += __shfl_xor(p, o);
        d0 = __shfl(p, 0);              // head0 = lanes 0..31
        d1 = __shfl(p, 32);             // head1 = lanes 32..63
    }

    float acc0[8] = {0, 0, 0, 0, 0, 0, 0, 0};
    float acc1[8] = {0, 0, 0, 0, 0, 0, 0, 0};
    float ds0 = 0.f, ds1 = 0.f;
#pragma unroll 2
    for (int j = start; j < end; j += 4) {
        int e = j + g;                  // uniform across the 16-lane group
        if (e < end) {
            int s = srcs[e];
            float2 a2 = *(const float2*)(asrc + 2 * s);   // broadcast in group
            float al0 = __expf(lrelu02(a2.x + d0));
            float al1 = __expf(lrelu02(a2.y + d1));
            if (l15 == 0) { ds0 += al0; ds1 += al1; }
            const bf16* row = xh + (size_t)s * 256 + l15 * 8;
            int4 v0 = *(const int4*)row;           // head0 slice
            int4 v1 = *(const int4*)(row + 128);   // head1 slice
            const int* w0 = (const int*)&v0;
            const int* w1 = (const int*)&v1;
#pragma unroll
            for (int t = 0; t < 4; ++t) {
                acc0[2 * t]     += __uint_as_float(((unsigned)w0[t]) << 16) * al0;
                acc0[2 * t + 1] += __uint_as_float(((unsigned)w0[t]) & 0xffff0000u) * al0;
                acc1[2 * t]     += __uint_as_float(((unsigned)w1[t]) << 16) * al1;
                acc1[2 * t + 1] += __uint_as_float(((unsigned)w1[t]) & 0xffff0000u) * al1;
            }
        }
    }
    // reduce across the 4 edge groups
#pragma unroll
    for (int t = 0; t < 8; ++t) {
        acc0[t] += __shfl_xor(acc0[t], 16); acc0[t] += __shfl_xor(acc0[t], 32);
        acc1[t] += __shfl_xor(acc1[t], 16); acc1[t] += __shfl_xor(acc1[t], 32);
    }
    ds0 += __shfl_xor(ds0, 16); ds0 += __shfl_xor(ds0, 32);
    ds1 += __shfl_xor(ds1, 16); ds1 += __shfl_xor(ds1, 32);
    ds0 = __shfl(ds0, 0); ds1 = __shfl(ds1, 0);
    const float inv0 = 1.f / (ds0 + 1e-16f);
    const float inv1 = 1.f / (ds1 + 1e-16f);
    float accm[8];
#pragma unroll
    for (int t = 0; t < 8; ++t)
        accm[t] = 0.5f * (acc0[t] * inv0 + acc1[t] * inv1);   // head mean

    if (lane < 16) {
        const int c0 = l15 * 8;
        const size_t base = (size_t)n * HID + c0;
        float xm[8];
        if (xidx) {
            int ia = xidx[2 * n], is_ = xidx[2 * n + 1];
#pragma unroll
            for (int t = 0; t < 8; ++t)
                xm[t] = 0.5f * (x0_val(c0 + t, ia, is_, n, embAl, embSl, xflt) +
                                x0_val(c0 + t, ia, is_, n, embAr, embSr, xflt));
        } else {
            int4 vl = *(const int4*)(xprev_l + base);
            int4 vr = *(const int4*)(xprev_r + base);
            const int* wl = (const int*)&vl;
            const int* wr = (const int*)&vr;
#pragma unroll
            for (int t = 0; t < 4; ++t) {
                xm[2 * t] = 0.5f * (__uint_as_float(((unsigned)wl[t]) << 16) +
                                    __uint_as_float(((unsigned)wr[t]) << 16));
                xm[2 * t + 1] = 0.5f * (__uint_as_float(((unsigned)wl[t]) & 0xffff0000u) +
                                        __uint_as_float(((unsigned)wr[t]) & 0xffff0000u));
            }
        }
        bf16 res[8];
#pragma unroll
        for (int t = 0; t < 8; ++t)
            res[t] = f2b(xm[t] + fmaxf(0.f, accm[t] + bias[c0 + t]));
        *(int4*)(outx + base) = *(const int4*)res;
    }
}

// ---------------------------------------------------------------- JK / final

__global__ __launch_bounds__(256) void jkfin_kernel(
    const float* __restrict__ sb, const bf16* __restrict__ xs0,
    const bf16* __restrict__ xs1, const bf16* __restrict__ xs2,
    bf16* __restrict__ jk) {
    int w = (blockIdx.x * blockDim.x + threadIdx.x) >> 6;
    int lane = threadIdx.x & 63;
    if (w >= N_NODES) return;
    float s0 = sb[w], s1 = sb[N_NODES + w], s2 = sb[2 * N_NODES + w];
    float m = fmaxf(s0, fmaxf(s1, s2));
    float a0 = __expf(s0 - m), a1 = __expf(s1 - m), a2 = __expf(s2 - m);
    float inv = 1.f / (a0 + a1 + a2);
    a0 *= inv; a1 *= inv; a2 *= inv;
    size_t gn = (size_t)w * HID + lane * 2;
#pragma unroll
    for (int t = 0; t < 2; ++t) {
        float v0 = b2f(xs0[gn + t]);
        float v1 = b2f(xs1[gn + t]);
        float v2 = b2f(xs2[gn + t]);
        jk[gn + t] = f2b(v0 * a0 + v1 * a1 + v2 * a2);
    }
}

__global__ __launch_bounds__(256) void final_kernel(
    const float* __restrict__ o0, const float* __restrict__ o1,
    const float* __restrict__ o2, const float* __restrict__ o3,
    const float* __restrict__ lw, float* __restrict__ out, int nloc, long long c3off) {
    int w = (blockIdx.x * blockDim.x + threadIdx.x) >> 6;
    int lane = threadIdx.x & 63;
    if (w >= nloc) return;
    size_t base = (size_t)w * HID;
    float w0 = lw[lane], w1 = lw[64 + lane];
    const float* op[4] = {o0, o1, o2, o3};
    float v[4][2];
    float s[4];
#pragma unroll
    for (int i = 0; i < 4; ++i) {
        v[i][0] = op[i][base + lane];
        v[i][1] = op[i][base + 64 + lane];
        float t = v[i][0] * w0 + v[i][1] * w1;
        for (int o = 1; o < 64; o <<= 1) t += __shfl_xor(t, o);
        s[i] = t;
    }
    float m = fmaxf(fmaxf(s[0], s[1]), fmaxf(s[2], s[3]));
    float e0 = __expf(s[0] - m), e1 = __expf(s[1] - m);
    float e2 = __expf(s[2] - m), e3 = __expf(s[3] - m);
    float inv = 1.f / (e0 + e1 + e2 + e3);
    float r0 = (v[0][0] * e0 + v[1][0] * e1 + v[2][0] * e2 + v[3][0] * e3) * inv;
    float r1 = (v[0][1] * e0 + v[1][1] * e1 + v[2][1] * e2 + v[3][1] * e3) * inv;
    size_t obase = (size_t)(c3off + w) * HID;
    out[obase + lane] = r0;
    out[obase + 64 + lane] = r1;
}

// ---------------------------------------------------------------- entry

static long long align1k(long long x) { return (x + 1023) & ~1023LL; }

extern "C" void kernel_launch(void* const* d_in, const int* in_sizes, int n_in,
                              void* d_out, int out_size, void* d_ws, size_t ws_size,
                              hipStream_t stream) {
    (void)in_sizes; (void)n_in; (void)out_size;
    const int*   x_idx   = (const int*)  d_in[0];
    const float* x_flt   = (const float*)d_in[1];
    const int*   ei_l    = (const int*)  d_in[2];
    const int*   ei_r    = (const int*)  d_in[3];
    const float* emb_aa  = (const float*)d_in[4];
    const float* emb_ss  = (const float*)d_in[5];
    const float* conv_W  = (const float*)d_in[6];
    const float* att_s   = (const float*)d_in[7];
    const float* att_d   = (const float*)d_in[8];
    const float* conv_b  = (const float*)d_in[9];
    const float* Wih     = (const float*)d_in[10];
    const float* Whh     = (const float*)d_in[11];
    const float* bih     = (const float*)d_in[12];
    const float* bhh     = (const float*)d_in[13];
    const float* jkw     = (const float*)d_in[14];
    const float* dummy_W = (const float*)d_in[16];
    const float* dummy_b = (const float*)d_in[17];
    const float* fin_W   = (const float*)d_in[18];
    const float* fin_b   = (const float*)d_in[19];
    const float* last_W  = (const float*)d_in[20];
    float* out = (float*)d_out;

    const long long S = (long long)N_NODES * HID;
    char* ws = (char*)d_ws;
    long long off = 0;

    // fixed-lifetime allocations
    bf16* hist = (bf16*)(ws + off);  off += align1k(6 * S * 2);          // 153.6 MB
    float* scores = (float*)(ws + off); off += align1k(6LL * N_NODES * 4);
    float* bsum   = (float*)(ws + off); off += align1k(4LL * G4 * 4);
    int* bsums    = (int*)(ws + off);  off += align1k(2LL * SCANB * 4);
    bf16* Wih_b   = (bf16*)(ws + off); off += align1k(4LL * G4 * HID * 2);
    bf16* Whh_b   = (bf16*)(ws + off); off += align1k(4LL * G4 * H2 * 2);
    bf16* dummyWt = (bf16*)(ws + off); off += align1k(2LL * 128 * 128 * 2);
    bf16* finWt   = (bf16*)(ws + off); off += align1k(4LL * 128 * 128 * 2);

    // BIG region overlays (ws ~256 MiB):
    //  stage0/1: [slot0: xh 51.2MB][slot1: CSR ints + asrc + convWt]
    //  stage2:   hA=BIG(38.4), c=BIG+slot0(38.4), hB=d_out scratch
    //  stage2-end/3: jkb = BIG base (51.2)
    char* BIG = ws + off;
    const long long slot0 = align1k(2 * S * 2);                         // 51.2 MB
    const long long slot1 = align1k((long long)N_NODES * H2 * 2);       // 38.4 MB
    const long long need = off + slot0 + slot1;

    if ((long long)ws_size < need) {   // diagnosable: 200000 + ws MiB
        float val = 200000.0f + (float)(ws_size >> 20);
        sentinel_kernel<<<(N_NODES * HID + 255) / 256, 256, 0, stream>>>(
            out, N_NODES * HID, val);
        return;
    }

    // stage0/1 views
    bf16* xh  = (bf16*)BIG;
    bf16* jkb = (bf16*)BIG;
    int* ibase = (int*)(BIG + slot0);
    int *deg[2], *offs[2], *pos[2], *srcs[2];
    long long io = 0;
    for (int b = 0; b < 2; ++b) {
        deg[b]  = ibase + io; io += N_NODES;
        offs[b] = ibase + io; io += N_NODES + 1;
        pos[b]  = ibase + io; io += N_NODES;
        srcs[b] = ibase + io; io += EL_TOT;
    }
    long long io4a = ((io * 4 + 15) & ~15LL);
    float* asrc = (float*)(BIG + slot0 + io4a);
    bf16* convWt = (bf16*)(BIG + slot0 + io4a + 2LL * N_NODES * 4);
    // stage2 views
    bf16* hA = (bf16*)BIG;               // 38.4 of slot0 (xh dead)
    bf16* hB = (bf16*)d_out;             // out as scratch
    bf16* cC = (bf16*)(BIG + slot0);     // slot1 (CSR dead)

    const float* embA[2] = {emb_aa, emb_aa + 26 * 123};
    const float* embS[2] = {emb_ss, emb_ss + 3 * 123};

    // ---- stage 0: weight conversion (LSTM weights gate-permuted) + CSR
    bsum_perm_kernel<<<12, 256, 0, stream>>>(bih, bhh, bsum);
    trans_kernel<<<(6 * 128 * 256 + 255) / 256, 256, 0, stream>>>(
        conv_W, convWt, 6, 128, 256);
    lstm_w_perm_kernel<<<(4 * G4 * HID + 255) / 256, 256, 0, stream>>>(
        Wih, Wih_b, HID);
    lstm_w_perm_kernel<<<(4 * G4 * H2 + 255) / 256, 256, 0, stream>>>(
        Whh, Whh_b, H2);
    trans_kernel<<<(2 * 128 * 128 + 255) / 256, 256, 0, stream>>>(
        dummy_W, dummyWt, 2, 128, 128);
    trans_kernel<<<(4 * 128 * 128 + 255) / 256, 256, 0, stream>>>(
        fin_W, finWt, 4, 128, 128);
    hipMemsetAsync(deg[0], 0, N_NODES * sizeof(int), stream);
    hipMemsetAsync(deg[1], 0, N_NODES * sizeof(int), stream);
    deg_kernel<<<(EL_TOT + 255) / 256, 256, 0, stream>>>(ei_l + N_EDGES, deg[0]);
    deg_kernel<<<(EL_TOT + 255) / 256, 256, 0, stream>>>(ei_r + N_EDGES, deg[1]);
    scan1_kernel<<<dim3(SCANB, 2), 1024, 0, stream>>>(
        deg[0], deg[1], pos[0], pos[1], bsums);
    scan2_kernel<<<1, 64, 0, stream>>>(bsums);
    scan3_kernel<<<dim3(SCANB, 2), 1024, 0, stream>>>(
        bsums, deg[0], deg[1], pos[0], pos[1], offs[0], offs[1], pos[0], pos[1]);
    fill_kernel<<<(EL_TOT + 255) / 256, 256, 0, stream>>>(
        ei_l, ei_l + N_EDGES, pos[0], srcs[0]);
    fill_kernel<<<(EL_TOT + 255) / 256, 256, 0, stream>>>(
        ei_r, ei_r + N_EDGES, pos[1], srcs[1]);

    // ---- stage 1: 3 GAT layers x 2 branches (a_src fused into GEMM epilogue,
    // plain store — no memset needed)
    for (int i = 0; i < 3; ++i) {
        for (int b = 0; b < 2; ++b) {
            const bf16* Wc = convWt + (size_t)(b * 3 + i) * 256 * 128;
            const float* as_ = att_s + (size_t)(b * 3 + i) * 2 * HID;
            if (i == 0) {
                mfma_gemm_x0_kernel<<<swz_grid(N_NODES, 2), 256, 0, stream>>>(
                    x_idx, x_flt, embA[b], embS[b], Wc, xh, N_NODES, 256,
                    as_, asrc);
            } else {
                mfma_gemm_kernel<bf16><<<swz_grid(N_NODES, 2), 256, 0, stream>>>(
                    hist + (size_t)(b * 3 + i - 1) * S, Wc, 128,
                    xh, nullptr, N_NODES, 256, as_, asrc);
            }
            const bf16* xpl = (i == 0) ? nullptr : hist + (size_t)(i - 1) * S;
            const bf16* xpr = (i == 0) ? nullptr : hist + (size_t)(3 + i - 1) * S;
            agg_kernel<<<25000, 256, 0, stream>>>(
                xh, asrc, att_d + (size_t)(b * 3 + i) * 2 * HID,
                offs[b], srcs[b], xpl, xpr,
                (i == 0) ? x_idx : nullptr, x_flt,
                embA[0], embS[0], embA[1], embS[1],
                conv_b + (size_t)(b * 3 + i) * HID, hist + (size_t)(b * 3 + i) * S);
        }
    }

    // ---- stage 2: bi-LSTM JK, fused cell epilogue, combos sequential;
    // h ping-pongs hA <-> hB (d_out scratch); st=2 skips dead h/c stores.
    hipMemsetAsync(scores, 0, (size_t)6 * N_NODES * 4, stream);
    const int gx = swz_grid(N_NODES, 6);
    for (int b = 0; b < 2; ++b) {
        for (int dir = 0; dir < 2; ++dir) {
            const int combo = b * 2 + dir;
            const bf16* Wi = Wih_b + (size_t)combo * G4 * HID;
            const bf16* Wh = Whh_b + (size_t)combo * G4 * H2;
            const float* bs = bsum + (size_t)combo * G4;
            const float* aw = jkw + (size_t)b * 2 * H2 + (size_t)dir * H2;
            for (int st = 0; st < 3; ++st) {
                int l = dir ? (2 - st) : st;
                const bf16* A = hist + (size_t)(b * 3 + l) * S;
                const bf16* hin = (st == 0) ? nullptr : ((st & 1) ? hA : hB);
                bf16* hout = (st & 1) ? hB : hA;
                lstm_gemm_kernel<<<gx, 256, 0, stream>>>(
                    A, Wi, hin, Wh, bs, cC, hout, aw,
                    scores + (size_t)(b * 3 + l) * N_NODES,
                    st == 0 ? 1 : 0, st == 2 ? 1 : 0, N_NODES);
            }
        }
    }
    for (int b = 0; b < 2; ++b)
        jkfin_kernel<<<25000, 256, 0, stream>>>(
            scores + (size_t)b * 3 * N_NODES,
            hist + (size_t)b * 3 * S, hist + (size_t)(b * 3 + 1) * S,
            hist + (size_t)(b * 3 + 2) * S, jkb + (size_t)b * S);

    // ---- stage 3: sq, outs, final combine (scratch = freed hist region)
    float* f3 = (float*)hist;
    bf16* jkl = jkb; bf16* jkr = jkb + S;
    for (long long c3 = 0; c3 < N_NODES; c3 += CH3) {
        int Rr = (int)((N_NODES - c3) < CH3 ? (N_NODES - c3) : CH3);
        float* o0 = f3;
        float* o1 = f3 + 1LL * CH3 * HID;
        float* o2 = f3 + 2LL * CH3 * HID;
        float* o3 = f3 + 3LL * CH3 * HID;
        bf16* sql = (bf16*)(f3 + 4LL * CH3 * HID);
        bf16* sqr = sql + (long long)CH3 * HID;
        mfma_gemm_b_kernel<bf16><<<dim3(swz_grid(Rr, 1), 2), 256, 0, stream>>>(
            jkl + c3 * HID, jkr + c3 * HID, nullptr, nullptr,
            dummyWt, sql, sqr, nullptr, nullptr, dummy_b, Rr);
        mfma_gemm_b_kernel<float><<<dim3(swz_grid(Rr, 1), 4), 256, 0, stream>>>(
            jkl + c3 * HID, sql, jkr + c3 * HID, sqr,
            finWt, o0, o1, o2, o3, fin_b, Rr);
        final_kernel<<<(Rr + 3) / 4, 256, 0, stream>>>(
            o0, o1, o2, o3, last_W, out, Rr, c3);
    }
}